// Round 11
// baseline (242.135 us; speedup 1.0000x reference)
//
#include <hip/hip_runtime.h>

#define D 64
#define K 1024
#define NROWS (32 * 4096)
#define NELEM (NROWS * D)
#define COMMIT 0.25f
#define DELTA 6e-5f

typedef __attribute__((ext_vector_type(8))) short short8v;   // 8 bf16
typedef __attribute__((ext_vector_type(4))) float f32x4;

static __device__ __forceinline__ float fence(float v) {
    asm("" : "+v"(v));
    return v;
}

// f32 -> bf16 bits, round-to-nearest-even (finite inputs only).
static __device__ __forceinline__ unsigned short f2bf(float f) {
    unsigned u = __float_as_uint(f);
    return (unsigned short)((u + 0x7FFFu + ((u >> 16) & 1u)) >> 16);
}

// Order-preserving float -> u32 map (handles negatives) and inverse.
static __device__ __forceinline__ unsigned fmap(float t) {
    unsigned u = __float_as_uint(t);
    return ((int)u < 0) ? ~u : (u | 0x80000000u);
}
static __device__ __forceinline__ float funmap(unsigned m) {
    return ((int)m < 0) ? __uint_as_float(m ^ 0x80000000u)
                        : __uint_as_float(~m);
}

// numpy pairwise_sum for n=64: 8 accumulators stride 8, then pairwise tree.
static __device__ __forceinline__ float np_sumsq64(const float* __restrict__ e) {
    float r[8];
#pragma unroll
    for (int j = 0; j < 8; ++j) r[j] = fence(e[j] * e[j]);
#pragma unroll
    for (int t = 1; t < 8; ++t)
#pragma unroll
        for (int j = 0; j < 8; ++j) r[j] = r[j] + fence(e[8 * t + j] * e[8 * t + j]);
    return ((r[0] + r[1]) + (r[2] + r[3])) + ((r[4] + r[5]) + (r[6] + r[7]));
}

// Bit-exact reference score: s = fl( fl(R+N) - 2*dot ), dot = ascending-i
// sequential FMA chain (validated absmax=0 in R2..R10).
static __device__ __forceinline__ float exact_score(
    const float* __restrict__ xrow, const float* __restrict__ erow, float R,
    float N) {
    float a = 0.0f;
#pragma unroll
    for (int i = 0; i < D; ++i) a = __builtin_fmaf(xrow[i], erow[i], a);
    return (R + N) - 2.0f * a;
}

// ---------------- Kernel 1: embedding prep ----------------
__global__ void prep_emb_kernel(const float* __restrict__ emb,
                                float* __restrict__ enorm,
                                unsigned short* __restrict__ e_hi,
                                unsigned short* __restrict__ e_lo,
                                float* __restrict__ loss_slot) {
    int k = blockIdx.x * blockDim.x + threadIdx.x;
    if (k == 0) *loss_slot = 0.0f;
    if (k >= K) return;
    enorm[k] = np_sumsq64(emb + k * D);
    const float* e = emb + k * D;
#pragma unroll
    for (int i = 0; i < D; ++i) {
        float v = e[i];
        unsigned short h = f2bf(v);
        float hf = __uint_as_float((unsigned)h << 16);
        e_hi[k * D + i] = h;
        e_lo[k * D + i] = f2bf(v - hf);  // v-hf exact (Sterbenz)
    }
}

// ---------------- Kernel 2: single-pass MFMA argmin + min2 + fused epilogue
// Block = 64 rows, 4 waves; wave w scans codes [256w,256w+256).
// t_k = N_k - 2*dot via 3-product bf16 hi/lo MFMA (|t - t_true| <= ~3e-6).
// Per output slot we track P1 = packed (fmap(t),code) u64 min AND M2 =
// second-smallest fmap(t) (multiset). Reference argmin can differ from the
// t-argmin only when the t-gap <= 2(eta_s + eps_m) ~ 2.8e-5 < DELTA=6e-5,
// so: gap > DELTA  ->  P1's code IS the reference argmin (strictly).
// Flagged rows (~1.5%) get a wave-parallel full bit-exact rescan with
// lexicographic (s,k) min = numpy first-index argmin.
// Epilogue (fused kernel 3): gather + straight-through write + loss atomic.
__global__ __launch_bounds__(256, 1) void argmin_kernel(
    const float* __restrict__ x, const float* __restrict__ emb,
    const float* __restrict__ enorm, const unsigned short* __restrict__ e_hi,
    const unsigned short* __restrict__ e_lo, float* __restrict__ out_q,
    float* __restrict__ idx_f, float* __restrict__ loss_slot) {
    const int l = threadIdx.x & 63;
    const int w = threadIdx.x >> 6;
    const int rowbase = blockIdx.x * 64;
    const int cbase = w * 256;

    __shared__ unsigned long long wP1[4][64];
    __shared__ unsigned wM2[4][64];
    __shared__ int bidx[64];
    __shared__ int rescue_list[64];
    __shared__ int rescue_cnt;
    __shared__ float wsum[4];
    if (threadIdx.x == 0) rescue_cnt = 0;

    // ---- A-fragments: x rows as bf16 hi/lo, built once, register-resident.
    // A layout (16x16x32): row = l&15, k = h*32 + (l>>4)*8 + i; B uses the
    // same per-lane k-permutation (validated absmax=0 in R10).
    short8v Ahi[4][2], Alo[4][2];
#pragma unroll
    for (int rt = 0; rt < 4; ++rt)
#pragma unroll
        for (int h = 0; h < 2; ++h) {
            const float* p = x + (size_t)(rowbase + rt * 16 + (l & 15)) * D +
                             h * 32 + (l >> 4) * 8;
            float4 q0 = *(const float4*)p;
            float4 q1 = *(const float4*)(p + 4);
            float f[8] = {q0.x, q0.y, q0.z, q0.w, q1.x, q1.y, q1.z, q1.w};
            short8v hi, lo;
#pragma unroll
            for (int i = 0; i < 8; ++i) {
                unsigned short hb = f2bf(f[i]);
                float hf = __uint_as_float((unsigned)hb << 16);
                hi[i] = (short)hb;
                lo[i] = (short)f2bf(f[i] - hf);
            }
            Ahi[rt][h] = hi;
            Alo[rt][h] = lo;
        }

    unsigned long long P1[16];
    unsigned M2[16];
#pragma unroll
    for (int s = 0; s < 16; ++s) {
        P1[s] = ~0ULL;
        M2[s] = 0xFFFFFFFFu;
    }

    // ---------------- single pass: min + second-min over 256 codes ---------
    for (int nt = 0; nt < 16; ++nt) {
        const int code = cbase + nt * 16 + (l & 15);
        const int koff = (l >> 4) * 8;
        const short8v Bhi0 = *(const short8v*)(e_hi + code * D + koff);
        const short8v Bhi1 = *(const short8v*)(e_hi + code * D + 32 + koff);
        const short8v Blo0 = *(const short8v*)(e_lo + code * D + koff);
        const short8v Blo1 = *(const short8v*)(e_lo + code * D + 32 + koff);
        const float Nc = enorm[code];
#pragma unroll
        for (int rt = 0; rt < 4; ++rt) {
            f32x4 acc = {0.f, 0.f, 0.f, 0.f};
            acc = __builtin_amdgcn_mfma_f32_16x16x32_bf16(Ahi[rt][0], Bhi0, acc, 0, 0, 0);
            acc = __builtin_amdgcn_mfma_f32_16x16x32_bf16(Ahi[rt][1], Bhi1, acc, 0, 0, 0);
            acc = __builtin_amdgcn_mfma_f32_16x16x32_bf16(Ahi[rt][0], Blo0, acc, 0, 0, 0);
            acc = __builtin_amdgcn_mfma_f32_16x16x32_bf16(Ahi[rt][1], Blo1, acc, 0, 0, 0);
            acc = __builtin_amdgcn_mfma_f32_16x16x32_bf16(Alo[rt][0], Bhi0, acc, 0, 0, 0);
            acc = __builtin_amdgcn_mfma_f32_16x16x32_bf16(Alo[rt][1], Bhi1, acc, 0, 0, 0);
#pragma unroll
            for (int r = 0; r < 4; ++r) {
                float t = __builtin_fmaf(-2.0f, acc[r], Nc);
                unsigned m = fmap(t);
                unsigned long long pk =
                    ((unsigned long long)m << 32) | (unsigned)code;
                const int s = rt * 4 + r;
                unsigned pm = (unsigned)(P1[s] >> 32);
                if (pk < P1[s]) {
                    M2[s] = M2[s] < pm ? M2[s] : pm;
                    P1[s] = pk;
                } else {
                    M2[s] = M2[s] < m ? M2[s] : m;
                }
            }
        }
    }

    // C/D layout: col = l&15 (code), row = (l>>4)*4 + r; the 16 lanes of a
    // row form a contiguous 16-lane group -> xor 1/2/4/8 butterfly.
#pragma unroll
    for (int s = 0; s < 16; ++s) {
#pragma unroll
        for (int off = 1; off < 16; off <<= 1) {
            unsigned long long po = __shfl_xor(P1[s], off);
            unsigned mo = __shfl_xor(M2[s], off);
            unsigned long long mx = P1[s] > po ? P1[s] : po;
            P1[s] = P1[s] < po ? P1[s] : po;
            unsigned mm = M2[s] < mo ? M2[s] : mo;
            unsigned sx = (unsigned)(mx >> 32);
            M2[s] = mm < sx ? mm : sx;
        }
    }
    if ((l & 15) == 0) {
        const int g = l >> 4;
#pragma unroll
        for (int rt = 0; rt < 4; ++rt)
#pragma unroll
            for (int r = 0; r < 4; ++r) {
                wP1[w][rt * 16 + g * 4 + r] = P1[rt * 4 + r];
                wM2[w][rt * 16 + g * 4 + r] = M2[rt * 4 + r];
            }
    }
    __syncthreads();

    // ---- cross-wave merge + flagging ----
    if (threadIdx.x < 64) {
        unsigned long long p = wP1[0][threadIdx.x];
        unsigned m2 = wM2[0][threadIdx.x];
#pragma unroll
        for (int ww = 1; ww < 4; ++ww) {
            unsigned long long q = wP1[ww][threadIdx.x];
            unsigned q2 = wM2[ww][threadIdx.x];
            unsigned long long mx = p > q ? p : q;
            p = p < q ? p : q;
            unsigned mm = m2 < q2 ? m2 : q2;
            unsigned sx = (unsigned)(mx >> 32);
            m2 = mm < sx ? mm : sx;
        }
        bidx[threadIdx.x] = (int)(p & 0xffffffffu);
        float f1 = funmap((unsigned)(p >> 32));
        float f2 = funmap(m2);
        if (f2 - f1 <= DELTA) {
            int pos = atomicAdd(&rescue_cnt, 1);
            rescue_list[pos] = threadIdx.x;
        }
    }
    __syncthreads();

    // ---- rescue: one wave per flagged row, full bit-exact rescan ----
    const int nres = rescue_cnt;
    for (int ri = w; ri < nres; ri += 4) {
        const int row = rescue_list[ri];
        const float* __restrict__ xrow = x + (size_t)(rowbase + row) * D;
        const float R = np_sumsq64(xrow);  // wave-uniform, bit-exact np chain
        unsigned long long best = ~0ULL;
        for (int j = 0; j < 16; ++j) {
            const int c = j * 64 + l;
            float sE = exact_score(xrow, emb + ((size_t)c << 6), R, enorm[c]);
            // sE ~ 64 > 0 -> direct bit ordering; low 32 = code -> first-idx
            unsigned long long pk =
                ((unsigned long long)__float_as_uint(sE) << 32) | (unsigned)c;
            best = pk < best ? pk : best;
        }
#pragma unroll
        for (int off = 1; off < 64; off <<= 1) {
            unsigned long long po = __shfl_xor(best, off);
            best = po < best ? po : best;
        }
        if (l == 0) bidx[row] = (int)(best & 0xffffffffu);
    }
    __syncthreads();

    // ---- fused epilogue: gather + straight-through + loss ----
    {
        const int row = threadIdx.x >> 2;
        const int d0 = (threadIdx.x & 3) * 16;
        const int bk = bidx[row];
        const float4* xq = (const float4*)(x + (size_t)(rowbase + row) * D + d0);
        const float4* eq = (const float4*)(emb + ((size_t)bk << 6) + d0);
        float4* oq = (float4*)(out_q + (size_t)(rowbase + row) * D + d0);
        float lsum = 0.f;
#pragma unroll
        for (int i = 0; i < 4; ++i) {
            float4 xv = xq[i];
            float4 ev = eq[i];
            float dx = ev.x - xv.x, dy = ev.y - xv.y, dz = ev.z - xv.z,
                  dw = ev.w - xv.w;
            float4 o;
            o.x = xv.x + dx;
            o.y = xv.y + dy;
            o.z = xv.z + dz;
            o.w = xv.w + dw;
            oq[i] = o;
            lsum = __builtin_fmaf(dx, dx, lsum);
            lsum = __builtin_fmaf(dy, dy, lsum);
            lsum = __builtin_fmaf(dz, dz, lsum);
            lsum = __builtin_fmaf(dw, dw, lsum);
        }
#pragma unroll
        for (int o = 32; o > 0; o >>= 1) lsum += __shfl_xor(lsum, o);
        if (l == 0) wsum[w] = lsum;
        __syncthreads();
        if (threadIdx.x == 0)
            atomicAdd(loss_slot, ((wsum[0] + wsum[1]) + (wsum[2] + wsum[3])) *
                                     ((1.0f + COMMIT) / (float)NELEM));
        if (threadIdx.x < 64)
            idx_f[rowbase + threadIdx.x] = (float)bidx[threadIdx.x];
    }
}

extern "C" void kernel_launch(void* const* d_in, const int* in_sizes, int n_in,
                              void* d_out, int out_size, void* d_ws,
                              size_t ws_size, hipStream_t stream) {
    const float* x = (const float*)d_in[0];    // [32,4096,64] f32
    const float* emb = (const float*)d_in[1];  // [1024,64] f32

    float* out = (float*)d_out;
    float* loss_slot = out;              // out[0]
    float* out_q = out + 1;              // out[1 .. 1+NELEM)
    float* idx_f = out + 1 + NELEM;      // indices as f32

    // workspace layout (16B-aligned slabs)
    float* enorm = (float*)d_ws;                                    // 4 KB
    unsigned short* e_hi = (unsigned short*)((char*)d_ws + 4096);   // 128 KB
    unsigned short* e_lo = (unsigned short*)((char*)d_ws + 135168); // 128 KB

    prep_emb_kernel<<<(K + 255) / 256, 256, 0, stream>>>(emb, enorm, e_hi,
                                                         e_lo, loss_slot);
    argmin_kernel<<<NROWS / 64, 256, 0, stream>>>(x, emb, enorm, e_hi, e_lo,
                                                  out_q, idx_f, loss_slot);
}

// Round 12
// 237.205 us; speedup vs baseline: 1.0208x; 1.0208x over previous
//
#include <hip/hip_runtime.h>

#define D 64
#define K 1024
#define NROWS (32 * 4096)
#define NELEM (NROWS * D)
#define COMMIT 0.25f
#define DELTA 6e-5f

typedef __attribute__((ext_vector_type(8))) short short8v;   // 8 bf16
typedef __attribute__((ext_vector_type(4))) float f32x4;
typedef unsigned long long u64;

static __device__ __forceinline__ float fence(float v) {
    asm("" : "+v"(v));
    return v;
}

// f32 -> bf16 bits, round-to-nearest-even (finite inputs only).
static __device__ __forceinline__ unsigned short f2bf(float f) {
    unsigned u = __float_as_uint(f);
    return (unsigned short)((u + 0x7FFFu + ((u >> 16) & 1u)) >> 16);
}

// Order-preserving float -> u32 map (handles negatives) and inverse.
static __device__ __forceinline__ unsigned fmap(float t) {
    unsigned u = __float_as_uint(t);
    return ((int)u < 0) ? ~u : (u | 0x80000000u);
}
static __device__ __forceinline__ float funmap(unsigned m) {
    return ((int)m < 0) ? __uint_as_float(m ^ 0x80000000u)
                        : __uint_as_float(~m);
}

// numpy pairwise_sum for n=64: 8 accumulators stride 8, then pairwise tree.
static __device__ __forceinline__ float np_sumsq64(const float* __restrict__ e) {
    float r[8];
#pragma unroll
    for (int j = 0; j < 8; ++j) r[j] = fence(e[j] * e[j]);
#pragma unroll
    for (int t = 1; t < 8; ++t)
#pragma unroll
        for (int j = 0; j < 8; ++j) r[j] = r[j] + fence(e[8 * t + j] * e[8 * t + j]);
    return ((r[0] + r[1]) + (r[2] + r[3])) + ((r[4] + r[5]) + (r[6] + r[7]));
}

// Bit-exact reference score: s = fl( fl(R+N) - 2*dot ), dot = ascending-i
// sequential FMA chain (validated absmax=0 in R2..R11).
static __device__ __forceinline__ float exact_score(
    const float* __restrict__ xrow, const float* __restrict__ erow, float R,
    float N) {
    float a = 0.0f;
#pragma unroll
    for (int i = 0; i < D; ++i) a = __builtin_fmaf(xrow[i], erow[i], a);
    return (R + N) - 2.0f * a;
}

// ---------------- Kernel 1: embedding prep ----------------
__global__ void prep_emb_kernel(const float* __restrict__ emb,
                                float* __restrict__ enorm,
                                unsigned short* __restrict__ e_hi,
                                unsigned short* __restrict__ e_lo,
                                float* __restrict__ loss_slot) {
    int k = blockIdx.x * blockDim.x + threadIdx.x;
    if (k == 0) *loss_slot = 0.0f;
    if (k >= K) return;
    enorm[k] = np_sumsq64(emb + k * D);
    const float* e = emb + k * D;
#pragma unroll
    for (int i = 0; i < D; ++i) {
        float v = e[i];
        unsigned short h = f2bf(v);
        float hf = __uint_as_float((unsigned)h << 16);
        e_hi[k * D + i] = h;
        e_lo[k * D + i] = f2bf(v - hf);  // v-hf exact (Sterbenz)
    }
}

#define FORSLOT(M) M(0) M(1) M(2) M(3) M(4) M(5) M(6) M(7) \
                   M(8) M(9) M(10) M(11) M(12) M(13) M(14) M(15)

// ---------------- Kernel 2: single-pass MFMA argmin (all-SSA state) --------
// Same algorithm as R11 (validated absmax=0): per-slot (min1,code) + min2
// over t = N_k - 2*dot (3-product hi/lo bf16 MFMA, err ~3e-6); rows whose
// t-gap <= DELTA get a wave-parallel bit-exact rescan. R11's regression was
// P1[]/M2[] C-arrays -> scratch (WRITE_SIZE 33 MB). ALL hot state is now
// named SSA scalars via X-macros: P1_0..15 (u64), M2_0..15 (u32),
// Ahi/Alo_rt_h (16x short8v). No allocas anywhere in the kernel.
__global__ __launch_bounds__(256, 1) void argmin_kernel(
    const float* __restrict__ x, const float* __restrict__ emb,
    const float* __restrict__ enorm, const unsigned short* __restrict__ e_hi,
    const unsigned short* __restrict__ e_lo, float* __restrict__ out_q,
    float* __restrict__ idx_f, float* __restrict__ loss_slot) {
    const int l = threadIdx.x & 63;
    const int w = threadIdx.x >> 6;
    const int rowbase = blockIdx.x * 64;
    const int cbase = w * 256;

    __shared__ u64 wP1[4][64];
    __shared__ unsigned wM2[4][64];
    __shared__ int bidx[64];
    __shared__ int rescue_list[64];
    __shared__ int rescue_cnt;
    __shared__ float wsum[4];
    if (threadIdx.x == 0) rescue_cnt = 0;

    // ---- A-fragments: named SSA short8v, built once.
    // A layout (16x16x32): row = l&15, k = h*32 + (l>>4)*8 + i; B uses the
    // same per-lane k-permutation (validated in R10/R11).
#define MKELT(hi, lo, i, v)                                                 \
    { unsigned short hb = f2bf(v);                                          \
      hi[i] = (short)hb;                                                    \
      lo[i] = (short)f2bf((v) - __uint_as_float((unsigned)hb << 16)); }
#define DECL_A(rt, h)                                                       \
    short8v Ahi_##rt##_##h, Alo_##rt##_##h;                                 \
    { const float* p = x + (size_t)(rowbase + rt * 16 + (l & 15)) * D +     \
                       h * 32 + (l >> 4) * 8;                               \
      float4 q0 = *(const float4*)p, q1 = *(const float4*)(p + 4);          \
      MKELT(Ahi_##rt##_##h, Alo_##rt##_##h, 0, q0.x)                        \
      MKELT(Ahi_##rt##_##h, Alo_##rt##_##h, 1, q0.y)                        \
      MKELT(Ahi_##rt##_##h, Alo_##rt##_##h, 2, q0.z)                        \
      MKELT(Ahi_##rt##_##h, Alo_##rt##_##h, 3, q0.w)                        \
      MKELT(Ahi_##rt##_##h, Alo_##rt##_##h, 4, q1.x)                        \
      MKELT(Ahi_##rt##_##h, Alo_##rt##_##h, 5, q1.y)                        \
      MKELT(Ahi_##rt##_##h, Alo_##rt##_##h, 6, q1.z)                        \
      MKELT(Ahi_##rt##_##h, Alo_##rt##_##h, 7, q1.w) }
    DECL_A(0, 0) DECL_A(0, 1) DECL_A(1, 0) DECL_A(1, 1)
    DECL_A(2, 0) DECL_A(2, 1) DECL_A(3, 0) DECL_A(3, 1)

    // ---- per-slot state: named SSA scalars.
#define DECL_S(s) u64 P1_##s = ~0ULL; unsigned M2_##s = 0xFFFFFFFFu;
    FORSLOT(DECL_S)

#define UPD(s, tval)                                                        \
    { float t = __builtin_fmaf(-2.0f, (tval), Nc);                          \
      unsigned m = fmap(t);                                                 \
      u64 pk = ((u64)m << 32) | (unsigned)code;                             \
      unsigned pm = (unsigned)(P1_##s >> 32);                               \
      if (pk < P1_##s) { M2_##s = M2_##s < pm ? M2_##s : pm; P1_##s = pk; } \
      else             { M2_##s = M2_##s < m  ? M2_##s : m; } }

#define MFMA6(rt, sA, sB, sC, sD)                                           \
    { f32x4 acc = {0.f, 0.f, 0.f, 0.f};                                     \
      acc = __builtin_amdgcn_mfma_f32_16x16x32_bf16(Ahi_##rt##_0, Bhi0, acc, 0, 0, 0); \
      acc = __builtin_amdgcn_mfma_f32_16x16x32_bf16(Ahi_##rt##_1, Bhi1, acc, 0, 0, 0); \
      acc = __builtin_amdgcn_mfma_f32_16x16x32_bf16(Ahi_##rt##_0, Blo0, acc, 0, 0, 0); \
      acc = __builtin_amdgcn_mfma_f32_16x16x32_bf16(Ahi_##rt##_1, Blo1, acc, 0, 0, 0); \
      acc = __builtin_amdgcn_mfma_f32_16x16x32_bf16(Alo_##rt##_0, Bhi0, acc, 0, 0, 0); \
      acc = __builtin_amdgcn_mfma_f32_16x16x32_bf16(Alo_##rt##_1, Bhi1, acc, 0, 0, 0); \
      UPD(sA, acc[0]) UPD(sB, acc[1]) UPD(sC, acc[2]) UPD(sD, acc[3]) }

    // ---------------- single pass: min + second-min over 256 codes ---------
    for (int nt = 0; nt < 16; ++nt) {
        const int code = cbase + nt * 16 + (l & 15);
        const int koff = (l >> 4) * 8;
        const short8v Bhi0 = *(const short8v*)(e_hi + code * D + koff);
        const short8v Bhi1 = *(const short8v*)(e_hi + code * D + 32 + koff);
        const short8v Blo0 = *(const short8v*)(e_lo + code * D + koff);
        const short8v Blo1 = *(const short8v*)(e_lo + code * D + 32 + koff);
        const float Nc = enorm[code];
        MFMA6(0, 0, 1, 2, 3)
        MFMA6(1, 4, 5, 6, 7)
        MFMA6(2, 8, 9, 10, 11)
        MFMA6(3, 12, 13, 14, 15)
    }

    // C/D layout: col = l&15 (code), row = (l>>4)*4 + r; 16-lane groups.
#define BSTEP(s, off)                                                       \
    { u64 po = __shfl_xor(P1_##s, off);                                     \
      unsigned mo = __shfl_xor(M2_##s, off);                                \
      u64 mx = P1_##s > po ? P1_##s : po;                                   \
      P1_##s = P1_##s < po ? P1_##s : po;                                   \
      unsigned mm = M2_##s < mo ? M2_##s : mo;                              \
      unsigned sx = (unsigned)(mx >> 32);                                   \
      M2_##s = mm < sx ? mm : sx; }
#define BFLY(s) BSTEP(s, 1) BSTEP(s, 2) BSTEP(s, 4) BSTEP(s, 8)
    FORSLOT(BFLY)

#define WRS(s)                                                              \
    if ((l & 15) == 0) {                                                    \
        wP1[w][((s) / 4) * 16 + (l >> 4) * 4 + ((s) % 4)] = P1_##s;         \
        wM2[w][((s) / 4) * 16 + (l >> 4) * 4 + ((s) % 4)] = M2_##s;         \
    }
    FORSLOT(WRS)
    __syncthreads();

    // ---- cross-wave merge + flagging ----
    if (threadIdx.x < 64) {
        u64 p = wP1[0][threadIdx.x];
        unsigned m2 = wM2[0][threadIdx.x];
#pragma unroll
        for (int ww = 1; ww < 4; ++ww) {
            u64 q = wP1[ww][threadIdx.x];
            unsigned q2 = wM2[ww][threadIdx.x];
            u64 mx = p > q ? p : q;
            p = p < q ? p : q;
            unsigned mm = m2 < q2 ? m2 : q2;
            unsigned sx = (unsigned)(mx >> 32);
            m2 = mm < sx ? mm : sx;
        }
        bidx[threadIdx.x] = (int)(p & 0xffffffffu);
        float f1 = funmap((unsigned)(p >> 32));
        float f2 = funmap(m2);
        if (f2 - f1 <= DELTA) {
            int pos = atomicAdd(&rescue_cnt, 1);
            rescue_list[pos] = threadIdx.x;
        }
    }
    __syncthreads();

    // ---- rescue: one wave per flagged row, full bit-exact rescan ----
    const int nres = rescue_cnt;
    for (int ri = w; ri < nres; ri += 4) {
        const int row = rescue_list[ri];
        const float* __restrict__ xrow = x + (size_t)(rowbase + row) * D;
        const float R = np_sumsq64(xrow);  // wave-uniform, bit-exact np chain
        u64 best = ~0ULL;
        for (int j = 0; j < 16; ++j) {
            const int c = j * 64 + l;
            float sE = exact_score(xrow, emb + ((size_t)c << 6), R, enorm[c]);
            // sE ~ 64 > 0 -> direct bit ordering; low 32 = code -> first-idx
            u64 pk = ((u64)__float_as_uint(sE) << 32) | (unsigned)c;
            best = pk < best ? pk : best;
        }
#pragma unroll
        for (int off = 1; off < 64; off <<= 1) {
            u64 po = __shfl_xor(best, off);
            best = po < best ? po : best;
        }
        if (l == 0) bidx[row] = (int)(best & 0xffffffffu);
    }
    __syncthreads();

    // ---- fused epilogue: gather + straight-through + loss ----
    {
        const int row = threadIdx.x >> 2;
        const int d0 = (threadIdx.x & 3) * 16;
        const int bk = bidx[row];
        const float4* xq = (const float4*)(x + (size_t)(rowbase + row) * D + d0);
        const float4* eq = (const float4*)(emb + ((size_t)bk << 6) + d0);
        float4* oq = (float4*)(out_q + (size_t)(rowbase + row) * D + d0);
        float lsum = 0.f;
#pragma unroll
        for (int i = 0; i < 4; ++i) {
            float4 xv = xq[i];
            float4 ev = eq[i];
            float dx = ev.x - xv.x, dy = ev.y - xv.y, dz = ev.z - xv.z,
                  dw = ev.w - xv.w;
            float4 o;
            o.x = xv.x + dx;
            o.y = xv.y + dy;
            o.z = xv.z + dz;
            o.w = xv.w + dw;
            oq[i] = o;
            lsum = __builtin_fmaf(dx, dx, lsum);
            lsum = __builtin_fmaf(dy, dy, lsum);
            lsum = __builtin_fmaf(dz, dz, lsum);
            lsum = __builtin_fmaf(dw, dw, lsum);
        }
#pragma unroll
        for (int o = 32; o > 0; o >>= 1) lsum += __shfl_xor(lsum, o);
        if (l == 0) wsum[w] = lsum;
        __syncthreads();
        if (threadIdx.x == 0)
            atomicAdd(loss_slot, ((wsum[0] + wsum[1]) + (wsum[2] + wsum[3])) *
                                     ((1.0f + COMMIT) / (float)NELEM));
        if (threadIdx.x < 64)
            idx_f[rowbase + threadIdx.x] = (float)bidx[threadIdx.x];
    }
}

extern "C" void kernel_launch(void* const* d_in, const int* in_sizes, int n_in,
                              void* d_out, int out_size, void* d_ws,
                              size_t ws_size, hipStream_t stream) {
    const float* x = (const float*)d_in[0];    // [32,4096,64] f32
    const float* emb = (const float*)d_in[1];  // [1024,64] f32

    float* out = (float*)d_out;
    float* loss_slot = out;              // out[0]
    float* out_q = out + 1;              // out[1 .. 1+NELEM)
    float* idx_f = out + 1 + NELEM;      // indices as f32

    // workspace layout (16B-aligned slabs)
    float* enorm = (float*)d_ws;                                    // 4 KB
    unsigned short* e_hi = (unsigned short*)((char*)d_ws + 4096);   // 128 KB
    unsigned short* e_lo = (unsigned short*)((char*)d_ws + 135168); // 128 KB

    prep_emb_kernel<<<(K + 255) / 256, 256, 0, stream>>>(emb, enorm, e_hi,
                                                         e_lo, loss_slot);
    argmin_kernel<<<NROWS / 64, 256, 0, stream>>>(x, emb, enorm, e_hi, e_lo,
                                                  out_q, idx_f, loss_slot);
}

// Round 13
// 166.695 us; speedup vs baseline: 1.4526x; 1.4230x over previous
//
#include <hip/hip_runtime.h>

#define D 64
#define K 1024
#define NROWS (32 * 4096)
#define NELEM (NROWS * D)
#define COMMIT 0.25f
#define DELTA 6e-5f

typedef __attribute__((ext_vector_type(8))) short short8v;   // 8 bf16
typedef __attribute__((ext_vector_type(4))) float f32x4;
typedef unsigned long long u64;

#define FORSLOT(M) M(0) M(1) M(2) M(3) M(4) M(5) M(6) M(7) \
                   M(8) M(9) M(10) M(11) M(12) M(13) M(14) M(15)

static __device__ __forceinline__ float fence(float v) {
    asm("" : "+v"(v));
    return v;
}

// f32 -> bf16 bits, round-to-nearest-even (finite inputs only).
static __device__ __forceinline__ unsigned short f2bf(float f) {
    unsigned u = __float_as_uint(f);
    return (unsigned short)((u + 0x7FFFu + ((u >> 16) & 1u)) >> 16);
}

// numpy pairwise_sum for n=64: 8 accumulators stride 8, then pairwise tree.
static __device__ __forceinline__ float np_sumsq64(const float* __restrict__ e) {
    float r[8];
#pragma unroll
    for (int j = 0; j < 8; ++j) r[j] = fence(e[j] * e[j]);
#pragma unroll
    for (int t = 1; t < 8; ++t)
#pragma unroll
        for (int j = 0; j < 8; ++j) r[j] = r[j] + fence(e[8 * t + j] * e[8 * t + j]);
    return ((r[0] + r[1]) + (r[2] + r[3])) + ((r[4] + r[5]) + (r[6] + r[7]));
}

// Bit-exact reference score: s = fl( fl(R+N) - 2*dot ), dot = ascending-i
// sequential FMA chain (validated absmax=0 in R2..R12).
static __device__ __forceinline__ float exact_score(
    const float* __restrict__ xrow, const float* __restrict__ erow, float R,
    float N) {
    float a = 0.0f;
#pragma unroll
    for (int i = 0; i < D; ++i) a = __builtin_fmaf(xrow[i], erow[i], a);
    return (R + N) - 2.0f * a;
}

// ---------------- Kernel 1: embedding prep ----------------
__global__ void prep_emb_kernel(const float* __restrict__ emb,
                                float* __restrict__ enorm,
                                unsigned short* __restrict__ e_hi,
                                unsigned short* __restrict__ e_lo,
                                float* __restrict__ loss_slot) {
    int k = blockIdx.x * blockDim.x + threadIdx.x;
    if (k == 0) *loss_slot = 0.0f;
    if (k >= K) return;
    enorm[k] = np_sumsq64(emb + k * D);
    const float* e = emb + k * D;
#pragma unroll
    for (int i = 0; i < D; ++i) {
        float v = e[i];
        unsigned short h = f2bf(v);
        float hf = __uint_as_float((unsigned)h << 16);
        e_hi[k * D + i] = h;
        e_lo[k * D + i] = f2bf(v - hf);  // v-hf exact (Sterbenz)
    }
}

// ---------------- Kernel 2: 2-pass MFMA argmin, pipelined, fused epilogue --
// Block = 64 rows, 4 waves; wave w scans codes [256w, 256w+256).
// t_k = N_k - 2*dot via 3-product bf16 hi/lo MFMA (err ~1.5e-7 vs true).
// Reference winner satisfies t_{k*} <= t_min + 1.63e-5 (two ulp(64)
// roundings + MFMA err), so candidates = {t <= gmin + DELTA}, DELTA=6e-5.
// Pass A: fminf-only min (cheap, 2 ops/slot). Pass B: bitwise-identical
// recompute (same MFMA sequence -> same t), collect candidates. 1 candidate
// (~97% rows): done. Else exact-score candidates, lexicographic (s,k) min =
// numpy first-index. Both nt-loops ROTATED: prefetch nt+1's B/enorm into
// separate named regs before the MFMA block so L2 latency hides (R12 lesson:
// MfmaUtil 8% = load-starved). All hot state named SSA (R11 lesson).
__global__ __launch_bounds__(256, 1) void argmin_kernel(
    const float* __restrict__ x, const float* __restrict__ emb,
    const float* __restrict__ enorm, const unsigned short* __restrict__ e_hi,
    const unsigned short* __restrict__ e_lo, float* __restrict__ out_q,
    float* __restrict__ idx_f, float* __restrict__ loss_slot) {
    const int l = threadIdx.x & 63;
    const int w = threadIdx.x >> 6;
    const int rowbase = blockIdx.x * 64;
    const int cbase = w * 256;

    __shared__ float wminA[4][64];
    __shared__ float gmin[64];
    __shared__ int cnt[64];
    __shared__ int clist[64][8];
    __shared__ int bidx[64];
    __shared__ float wsum[4];

    // ---- A-fragments: named SSA short8v (validated R10-R12).
    // A layout (16x16x32): row = l&15, k = h*32 + (l>>4)*8 + i; B uses the
    // same per-lane k-permutation.
#define MKELT(hi, lo, i, v)                                                 \
    { unsigned short hb = f2bf(v);                                          \
      hi[i] = (short)hb;                                                    \
      lo[i] = (short)f2bf((v) - __uint_as_float((unsigned)hb << 16)); }
#define DECL_A(rt, h)                                                       \
    short8v Ahi_##rt##_##h, Alo_##rt##_##h;                                 \
    { const float* p = x + (size_t)(rowbase + rt * 16 + (l & 15)) * D +     \
                       h * 32 + (l >> 4) * 8;                               \
      float4 q0 = *(const float4*)p, q1 = *(const float4*)(p + 4);          \
      MKELT(Ahi_##rt##_##h, Alo_##rt##_##h, 0, q0.x)                        \
      MKELT(Ahi_##rt##_##h, Alo_##rt##_##h, 1, q0.y)                        \
      MKELT(Ahi_##rt##_##h, Alo_##rt##_##h, 2, q0.z)                        \
      MKELT(Ahi_##rt##_##h, Alo_##rt##_##h, 3, q0.w)                        \
      MKELT(Ahi_##rt##_##h, Alo_##rt##_##h, 4, q1.x)                        \
      MKELT(Ahi_##rt##_##h, Alo_##rt##_##h, 5, q1.y)                        \
      MKELT(Ahi_##rt##_##h, Alo_##rt##_##h, 6, q1.z)                        \
      MKELT(Ahi_##rt##_##h, Alo_##rt##_##h, 7, q1.w) }
    DECL_A(0, 0) DECL_A(0, 1) DECL_A(1, 0) DECL_A(1, 1)
    DECL_A(2, 0) DECL_A(2, 1) DECL_A(3, 0) DECL_A(3, 1)

    const int koff = (l >> 4) * 8;
    const size_t b0 = (size_t)(cbase + (l & 15)) * D + koff;

    // slot s = rt*4 + r maps to row (s/4)*16 + (l>>4)*4 + (s%4)
#define SLOTROW(s) (((s) / 4) * 16 + (l >> 4) * 4 + ((s) % 4))

    // =================== PASS A: fminf min ===================
#define DECL_MA(s) float mA_##s = 3.402823466e+38f;
    FORSLOT(DECL_MA)
    {
        const unsigned short* ph = e_hi + b0;
        const unsigned short* pl = e_lo + b0;
        const float* pe = enorm + cbase + (l & 15);
        short8v cH0 = *(const short8v*)ph;
        short8v cH1 = *(const short8v*)(ph + 32);
        short8v cL0 = *(const short8v*)pl;
        short8v cL1 = *(const short8v*)(pl + 32);
        float cNc = *pe;
#define MFMA6A(rt, sA, sB, sC, sD)                                          \
    { f32x4 acc = {0.f, 0.f, 0.f, 0.f};                                     \
      acc = __builtin_amdgcn_mfma_f32_16x16x32_bf16(Ahi_##rt##_0, Bhi0, acc, 0, 0, 0); \
      acc = __builtin_amdgcn_mfma_f32_16x16x32_bf16(Ahi_##rt##_1, Bhi1, acc, 0, 0, 0); \
      acc = __builtin_amdgcn_mfma_f32_16x16x32_bf16(Ahi_##rt##_0, Blo0, acc, 0, 0, 0); \
      acc = __builtin_amdgcn_mfma_f32_16x16x32_bf16(Ahi_##rt##_1, Blo1, acc, 0, 0, 0); \
      acc = __builtin_amdgcn_mfma_f32_16x16x32_bf16(Alo_##rt##_0, Bhi0, acc, 0, 0, 0); \
      acc = __builtin_amdgcn_mfma_f32_16x16x32_bf16(Alo_##rt##_1, Bhi1, acc, 0, 0, 0); \
      mA_##sA = fminf(mA_##sA, __builtin_fmaf(-2.0f, acc[0], Nc));          \
      mA_##sB = fminf(mA_##sB, __builtin_fmaf(-2.0f, acc[1], Nc));          \
      mA_##sC = fminf(mA_##sC, __builtin_fmaf(-2.0f, acc[2], Nc));          \
      mA_##sD = fminf(mA_##sD, __builtin_fmaf(-2.0f, acc[3], Nc)); }
        for (int nt = 0; nt < 16; ++nt) {
            short8v Bhi0 = cH0, Bhi1 = cH1, Blo0 = cL0, Blo1 = cL1;
            float Nc = cNc;
            if (nt < 15) {  // prefetch next tile (uniform branch)
                ph += 1024; pl += 1024; pe += 16;
                cH0 = *(const short8v*)ph;
                cH1 = *(const short8v*)(ph + 32);
                cL0 = *(const short8v*)pl;
                cL1 = *(const short8v*)(pl + 32);
                cNc = *pe;
            }
            MFMA6A(0, 0, 1, 2, 3)
            MFMA6A(1, 4, 5, 6, 7)
            MFMA6A(2, 8, 9, 10, 11)
            MFMA6A(3, 12, 13, 14, 15)
        }
    }
    // C/D layout: col = l&15 (code), row-group = 16 contiguous lanes.
#define BFA(s)                                                              \
    mA_##s = fminf(mA_##s, __shfl_xor(mA_##s, 1));                          \
    mA_##s = fminf(mA_##s, __shfl_xor(mA_##s, 2));                          \
    mA_##s = fminf(mA_##s, __shfl_xor(mA_##s, 4));                          \
    mA_##s = fminf(mA_##s, __shfl_xor(mA_##s, 8));
    FORSLOT(BFA)
#define WRA(s) if ((l & 15) == 0) wminA[w][SLOTROW(s)] = mA_##s;
    FORSLOT(WRA)
    __syncthreads();
    if (threadIdx.x < 64) {
        gmin[threadIdx.x] =
            fminf(fminf(wminA[0][threadIdx.x], wminA[1][threadIdx.x]),
                  fminf(wminA[2][threadIdx.x], wminA[3][threadIdx.x]));
        cnt[threadIdx.x] = 0;
    }
    __syncthreads();

    // =================== PASS B: candidate collection ===================
#define DECL_T(s) const float thr_##s = gmin[SLOTROW(s)] + DELTA;
    FORSLOT(DECL_T)
    {
        const unsigned short* ph = e_hi + b0;
        const unsigned short* pl = e_lo + b0;
        const float* pe = enorm + cbase + (l & 15);
        short8v cH0 = *(const short8v*)ph;
        short8v cH1 = *(const short8v*)(ph + 32);
        short8v cL0 = *(const short8v*)pl;
        short8v cL1 = *(const short8v*)(pl + 32);
        float cNc = *pe;
#define CHK(s, tval)                                                        \
    { float t = __builtin_fmaf(-2.0f, (tval), Nc);                          \
      if (t <= thr_##s) {                                                   \
          int row = SLOTROW(s);                                             \
          int pos = atomicAdd(&cnt[row], 1);                                \
          if (pos < 8) clist[row][pos] = code;                              \
      } }
#define MFMA6B(rt, sA, sB, sC, sD)                                          \
    { f32x4 acc = {0.f, 0.f, 0.f, 0.f};                                     \
      acc = __builtin_amdgcn_mfma_f32_16x16x32_bf16(Ahi_##rt##_0, Bhi0, acc, 0, 0, 0); \
      acc = __builtin_amdgcn_mfma_f32_16x16x32_bf16(Ahi_##rt##_1, Bhi1, acc, 0, 0, 0); \
      acc = __builtin_amdgcn_mfma_f32_16x16x32_bf16(Ahi_##rt##_0, Blo0, acc, 0, 0, 0); \
      acc = __builtin_amdgcn_mfma_f32_16x16x32_bf16(Ahi_##rt##_1, Blo1, acc, 0, 0, 0); \
      acc = __builtin_amdgcn_mfma_f32_16x16x32_bf16(Alo_##rt##_0, Bhi0, acc, 0, 0, 0); \
      acc = __builtin_amdgcn_mfma_f32_16x16x32_bf16(Alo_##rt##_1, Bhi1, acc, 0, 0, 0); \
      CHK(sA, acc[0]) CHK(sB, acc[1]) CHK(sC, acc[2]) CHK(sD, acc[3]) }
        int code = cbase + (l & 15);
        for (int nt = 0; nt < 16; ++nt) {
            short8v Bhi0 = cH0, Bhi1 = cH1, Blo0 = cL0, Blo1 = cL1;
            float Nc = cNc;
            if (nt < 15) {
                ph += 1024; pl += 1024; pe += 16;
                cH0 = *(const short8v*)ph;
                cH1 = *(const short8v*)(ph + 32);
                cL0 = *(const short8v*)pl;
                cL1 = *(const short8v*)(pl + 32);
                cNc = *pe;
            }
            MFMA6B(0, 0, 1, 2, 3)
            MFMA6B(1, 4, 5, 6, 7)
            MFMA6B(2, 8, 9, 10, 11)
            MFMA6B(3, 12, 13, 14, 15)
            code += 16;
        }
    }
    __syncthreads();

    // ---- select / rescue (1 thread per row) ----
    if (threadIdx.x < 64) {
        const int row = threadIdx.x;
        const int n = cnt[row];
        int bk;
        if (n == 1) {
            bk = clist[row][0];
        } else {
            const float* xrow = x + (size_t)(rowbase + row) * D;
            const float R = np_sumsq64(xrow);
            float sb = 3.402823466e+38f;
            int kb = 0x7fffffff;
            if (n <= 8) {
                for (int i = 0; i < n; ++i) {
                    int c = clist[row][i];
                    float s = exact_score(xrow, emb + ((size_t)c << 6), R,
                                          enorm[c]);
                    if (s < sb || (s == sb && c < kb)) { sb = s; kb = c; }
                }
            } else {  // clist overflow: full exact scan (essentially never)
                for (int c = 0; c < K; ++c) {
                    float s = exact_score(xrow, emb + ((size_t)c << 6), R,
                                          enorm[c]);
                    if (s < sb || (s == sb && c < kb)) { sb = s; kb = c; }
                }
            }
            bk = kb;
        }
        bidx[row] = bk;
        idx_f[rowbase + row] = (float)bk;
    }
    __syncthreads();

    // ---- fused epilogue: gather + straight-through + loss ----
    {
        const int row = threadIdx.x >> 2;
        const int d0 = (threadIdx.x & 3) * 16;
        const int bk = bidx[row];
        const float4* xq = (const float4*)(x + (size_t)(rowbase + row) * D + d0);
        const float4* eq = (const float4*)(emb + ((size_t)bk << 6) + d0);
        float4* oq = (float4*)(out_q + (size_t)(rowbase + row) * D + d0);
        float lsum = 0.f;
#pragma unroll
        for (int i = 0; i < 4; ++i) {
            float4 xv = xq[i];
            float4 ev = eq[i];
            float dx = ev.x - xv.x, dy = ev.y - xv.y, dz = ev.z - xv.z,
                  dw = ev.w - xv.w;
            float4 o;
            o.x = xv.x + dx;
            o.y = xv.y + dy;
            o.z = xv.z + dz;
            o.w = xv.w + dw;
            oq[i] = o;
            lsum = __builtin_fmaf(dx, dx, lsum);
            lsum = __builtin_fmaf(dy, dy, lsum);
            lsum = __builtin_fmaf(dz, dz, lsum);
            lsum = __builtin_fmaf(dw, dw, lsum);
        }
#pragma unroll
        for (int o = 32; o > 0; o >>= 1) lsum += __shfl_xor(lsum, o);
        if (l == 0) wsum[w] = lsum;
        __syncthreads();
        if (threadIdx.x == 0)
            atomicAdd(loss_slot, ((wsum[0] + wsum[1]) + (wsum[2] + wsum[3])) *
                                     ((1.0f + COMMIT) / (float)NELEM));
    }
}

extern "C" void kernel_launch(void* const* d_in, const int* in_sizes, int n_in,
                              void* d_out, int out_size, void* d_ws,
                              size_t ws_size, hipStream_t stream) {
    const float* x = (const float*)d_in[0];    // [32,4096,64] f32
    const float* emb = (const float*)d_in[1];  // [1024,64] f32

    float* out = (float*)d_out;
    float* loss_slot = out;              // out[0]
    float* out_q = out + 1;              // out[1 .. 1+NELEM)
    float* idx_f = out + 1 + NELEM;      // indices as f32

    // workspace layout (16B-aligned slabs)
    float* enorm = (float*)d_ws;                                    // 4 KB
    unsigned short* e_hi = (unsigned short*)((char*)d_ws + 4096);   // 128 KB
    unsigned short* e_lo = (unsigned short*)((char*)d_ws + 135168); // 128 KB

    prep_emb_kernel<<<(K + 255) / 256, 256, 0, stream>>>(emb, enorm, e_hi,
                                                         e_lo, loss_slot);
    argmin_kernel<<<NROWS / 64, 256, 0, stream>>>(x, emb, enorm, e_hi, e_lo,
                                                  out_q, idx_f, loss_slot);
}